// Round 7
// baseline (583.587 us; speedup 1.0000x reference)
//
#include <hip/hip_runtime.h>
#include <cstdint>
#include <math.h>

#define B_ 16
#define N_ 2048
#define C_ 64
#define O_ 64
#define K_ 20
#define P_ (B_*N_)   // 32768 positions
#define MSEL 40      // f32 screening superset; re-ranked exactly below

// ---------------------------------------------------------------------------
// proj: xx[p] (f32 screen + f64 exact); HC[p][o] = W[o,0:64].x_p + bias[o];
//       Y[p][o] = W[o,64:128].x_p
// ---------------------------------------------------------------------------
__global__ __launch_bounds__(256) void proj_kernel(
    const float* __restrict__ x, const float* __restrict__ W,
    const float* __restrict__ bias,
    float* __restrict__ xx, double* __restrict__ xx64,
    float* __restrict__ HC, float* __restrict__ Y)
{
  __shared__ float Wt[128][65];      // [c2][o], padded
  int t = threadIdx.x;
#pragma unroll
  for (int i = 0; i < 32; ++i) {
    int flat = t + 256 * i;          // o = flat>>7, c2 = flat&127
    Wt[flat & 127][flat >> 7] = W[flat];
  }
  __syncthreads();
  int lane = t & 63;
  int w = t >> 6;
  float bo = bias[lane];
  int pbase = blockIdx.x * 64 + w * 16;
  for (int g = 0; g < 4; ++g) {
    int p0 = pbase + g * 4;
    float xv0 = x[(size_t)(p0 + 0) * 64 + lane];
    float xv1 = x[(size_t)(p0 + 1) * 64 + lane];
    float xv2 = x[(size_t)(p0 + 2) * 64 + lane];
    float xv3 = x[(size_t)(p0 + 3) * 64 + lane];
    float hc0 = bo, hc1 = bo, hc2 = bo, hc3 = bo;
    float y0 = 0.f, y1 = 0.f, y2 = 0.f, y3 = 0.f;
#pragma unroll
    for (int c = 0; c < 64; ++c) {
      float w1 = Wt[c][lane];
      float w2 = Wt[64 + c][lane];
      float a0 = __shfl(xv0, c);
      float a1 = __shfl(xv1, c);
      float a2 = __shfl(xv2, c);
      float a3 = __shfl(xv3, c);
      hc0 += a0 * w1; y0 += a0 * w2;
      hc1 += a1 * w1; y1 += a1 * w2;
      hc2 += a2 * w1; y2 += a2 * w2;
      hc3 += a3 * w1; y3 += a3 * w2;
    }
    HC[(size_t)(p0 + 0) * 64 + lane] = hc0;
    HC[(size_t)(p0 + 1) * 64 + lane] = hc1;
    HC[(size_t)(p0 + 2) * 64 + lane] = hc2;
    HC[(size_t)(p0 + 3) * 64 + lane] = hc3;
    Y[(size_t)(p0 + 0) * 64 + lane] = y0;
    Y[(size_t)(p0 + 1) * 64 + lane] = y1;
    Y[(size_t)(p0 + 2) * 64 + lane] = y2;
    Y[(size_t)(p0 + 3) * 64 + lane] = y3;
    // row norms in f64 (exact re-rank uses these)
    double s0 = (double)xv0 * xv0, s1 = (double)xv1 * xv1;
    double s2 = (double)xv2 * xv2, s3 = (double)xv3 * xv3;
#pragma unroll
    for (int off = 32; off; off >>= 1) {
      s0 += __shfl_xor(s0, off);
      s1 += __shfl_xor(s1, off);
      s2 += __shfl_xor(s2, off);
      s3 += __shfl_xor(s3, off);
    }
    if (lane < 4) {
      double sv = (lane == 0) ? s0 : (lane == 1) ? s1 : (lane == 2) ? s2 : s3;
      xx[p0 + lane] = (float)sv;
      xx64[p0 + lane] = sv;
    }
  }
}

// ---------------------------------------------------------------------------
// dist: f32 screening, per batch, tile 128x128, 8x8 micro-tile per thread.
// ---------------------------------------------------------------------------
__global__ __launch_bounds__(256) void dist_kernel(
    const float* __restrict__ x, const float* __restrict__ xx,
    float* __restrict__ dist, int b0)
{
  int b = b0 + blockIdx.z;
  const float* xb = x + (size_t)b * N_ * 64;
  const float* xxb = xx + (size_t)b * N_;
  int it = blockIdx.y * 128, jt = blockIdx.x * 128;
  __shared__ float Xi[64][128];
  __shared__ float Xj[64][128];
  int t = threadIdx.x;
  {
    int r = t >> 1, half = t & 1;
    const float* si = xb + (size_t)(it + r) * 64 + half * 32;
    const float* sj = xb + (size_t)(jt + r) * 64 + half * 32;
#pragma unroll
    for (int q = 0; q < 8; ++q) {
      float4 vi = *(const float4*)(si + q * 4);
      float4 vj = *(const float4*)(sj + q * 4);
      int c0 = half * 32 + q * 4;
      Xi[c0 + 0][r] = vi.x; Xi[c0 + 1][r] = vi.y;
      Xi[c0 + 2][r] = vi.z; Xi[c0 + 3][r] = vi.w;
      Xj[c0 + 0][r] = vj.x; Xj[c0 + 1][r] = vj.y;
      Xj[c0 + 2][r] = vj.z; Xj[c0 + 3][r] = vj.w;
    }
  }
  __syncthreads();
  int tx = t & 15, ty = t >> 4;
  float acc[8][8];
#pragma unroll
  for (int i = 0; i < 8; ++i)
#pragma unroll
    for (int j = 0; j < 8; ++j) acc[i][j] = 0.f;
#pragma unroll 4
  for (int c = 0; c < 64; ++c) {
    float4 a0 = *(const float4*)&Xi[c][ty * 8];
    float4 a1 = *(const float4*)&Xi[c][ty * 8 + 4];
    float4 b0v = *(const float4*)&Xj[c][tx * 8];
    float4 b1v = *(const float4*)&Xj[c][tx * 8 + 4];
    float av[8] = {a0.x, a0.y, a0.z, a0.w, a1.x, a1.y, a1.z, a1.w};
    float bv[8] = {b0v.x, b0v.y, b0v.z, b0v.w, b1v.x, b1v.y, b1v.z, b1v.w};
#pragma unroll
    for (int i = 0; i < 8; ++i)
#pragma unroll
      for (int j = 0; j < 8; ++j) acc[i][j] += av[i] * bv[j];
  }
  float xi[8], xj[8];
#pragma unroll
  for (int i = 0; i < 8; ++i) xi[i] = xxb[it + ty * 8 + i];
#pragma unroll
  for (int j = 0; j < 8; ++j) xj[j] = xxb[jt + tx * 8 + j];
  float* drow = dist + ((size_t)blockIdx.z * N_ + (it + ty * 8)) * N_ + jt + tx * 8;
#pragma unroll
  for (int i = 0; i < 8; ++i) {
    float4 o0, o1;
    o0.x = (xi[i] + xj[0]) - 2.f * acc[i][0];
    o0.y = (xi[i] + xj[1]) - 2.f * acc[i][1];
    o0.z = (xi[i] + xj[2]) - 2.f * acc[i][2];
    o0.w = (xi[i] + xj[3]) - 2.f * acc[i][3];
    o1.x = (xi[i] + xj[4]) - 2.f * acc[i][4];
    o1.y = (xi[i] + xj[5]) - 2.f * acc[i][5];
    o1.z = (xi[i] + xj[6]) - 2.f * acc[i][6];
    o1.w = (xi[i] + xj[7]) - 2.f * acc[i][7];
    *(float4*)(drow + (size_t)i * N_) = o0;
    *(float4*)(drow + (size_t)i * N_ + 4) = o1;
  }
}

// ---------------------------------------------------------------------------
// topk: stage 1 = f32 radix-select top-MSEL superset. stage 2 = exact f64
// keys for the candidates; order by (f32(key) DESC, index DESC) — i.e. exact
// values, with numpy reversed-stable-argsort tie semantics at f32-bit ties.
// ---------------------------------------------------------------------------
__global__ __launch_bounds__(64) void topk_kernel(
    const float* __restrict__ dist, const float* __restrict__ x,
    const double* __restrict__ xx64, int* __restrict__ idxOut, int b0)
{
  int row = blockIdx.x;                       // row within chunk
  size_t p = (size_t)b0 * N_ + row;           // global position
  int b = (int)(p >> 11);
  const float* drow = dist + (size_t)row * N_;
  int lane = threadIdx.x;
  __shared__ int hist[256];
  __shared__ unsigned int candV[64];
  __shared__ int candI[64];
  __shared__ int selI[MSEL];
  __shared__ double sxd[64];

  unsigned int u[32];
#pragma unroll
  for (int s = 0; s < 32; ++s) {
    unsigned int ub = __float_as_uint(drow[lane + 64 * s]);
    u[s] = ub ^ ((unsigned)((int)ub >> 31) | 0x80000000u);
  }
  unsigned long long ltm = (1ull << lane) - 1ull;
  int defCount = 0;
  unsigned int prefix = 0;
  int inBin = 0, Bstar = 0;
  int shift;
  for (shift = 24; shift >= 0; shift -= 8) {
    hist[lane] = 0; hist[lane + 64] = 0; hist[lane + 128] = 0; hist[lane + 192] = 0;
    __syncthreads();
    int need = MSEL - defCount;
#pragma unroll
    for (int s = 0; s < 32; ++s) {
      bool m = (shift == 24) || ((u[s] >> (shift + 8)) == prefix);
      if (m) atomicAdd(&hist[(u[s] >> shift) & 0xFF], 1);
    }
    __syncthreads();
    int h0 = hist[4 * lane], h1 = hist[4 * lane + 1];
    int h2 = hist[4 * lane + 2], h3 = hist[4 * lane + 3];
    int laneTot = h0 + h1 + h2 + h3;
    int v = laneTot;
#pragma unroll
    for (int off = 1; off < 64; off <<= 1) {
      int nv = __shfl_down(v, off);
      if (lane + off < 64) v += nv;
    }
    int S = v - laneTot;                       // count in lanes > me
    int a3 = S, a2 = S + h3, a1 = a2 + h2, a0 = a1 + h1;
    int ksel = -1;
    if (a0 < need && a0 + h0 >= need) ksel = 0;
    if (a1 < need && a1 + h1 >= need) ksel = 1;
    if (a2 < need && a2 + h2 >= need) ksel = 2;
    if (a3 < need && a3 + h3 >= need) ksel = 3;
    unsigned long long bm = __ballot(ksel >= 0);
    int lsel = __ffsll((long long)bm) - 1;
    int kk = __shfl(ksel, lsel);
    Bstar = 4 * lsel + kk;
    int hS = (ksel == 0) ? h0 : (ksel == 1) ? h1 : (ksel == 2) ? h2 : h3;
    inBin = __shfl(hS, lsel);
    // collect definite members (bin > Bstar) into candidate list
    int cnt = 0;
#pragma unroll
    for (int s = 0; s < 32; ++s) {
      bool m = (shift == 24) || ((u[s] >> (shift + 8)) == prefix);
      bool dc = m && (int)((u[s] >> shift) & 0xFF) > Bstar;
      unsigned long long mask = __ballot(dc);
      if (dc) {
        int pos = cnt + __popcll(mask & ltm);
        selI[defCount + pos] = lane + 64 * s;
      }
      cnt += __popcll(mask);
    }
    defCount += cnt;
    if (inBin <= 64 || shift == 0) break;
    prefix = (prefix << 8) | (unsigned)Bstar;
  }
  int need2 = MSEL - defCount;                 // >= 1 by construction
  // boundary-bin candidates fill remaining superset slots (screening order)
  {
    int cc = 0;
#pragma unroll
    for (int s = 0; s < 32; ++s) {
      bool m = (shift == 24) || ((u[s] >> (shift + 8)) == prefix);
      bool qc = m && (int)((u[s] >> shift) & 0xFF) == Bstar;
      unsigned long long mask = __ballot(qc);
      if (qc) {
        int pos = cc + __popcll(mask & ltm);
        if (pos < 64) { candV[pos] = u[s]; candI[pos] = lane + 64 * s; }
      }
      cc += __popcll(mask);
    }
    __syncthreads();
    int M = inBin < 64 ? inBin : 64;
    unsigned long long comp = 0ull;
    int myI = 0;
    if (lane < M) {
      myI = candI[lane];
      comp = ((unsigned long long)candV[lane] << 32) | (unsigned)(2047 - myI);
    }
    for (int tsel = 0; tsel < need2; ++tsel) {
      unsigned long long best = comp;
#pragma unroll
      for (int off = 32; off; off >>= 1) {
        unsigned long long o2 = __shfl_xor(best, off);
        if (o2 > best) best = o2;
      }
      if (comp == best && comp != 0ull) {
        selI[defCount + tsel] = myI;
        comp = 0ull;
      }
    }
  }
  __syncthreads();
  // ---- stage 2: exact f64 keys; order (f32(key) desc, index DESC) ----
  sxd[lane] = (double)x[p * 64 + lane];
  __syncthreads();
  unsigned long long comp = 0ull;
  if (lane < MSEL) {
    int j = selI[lane];
    const float* xj = x + ((size_t)b * N_ + j) * 64;
    double acc = 0.0;
#pragma unroll 8
    for (int c = 0; c < 64; ++c) acc = fma((double)xj[c], sxd[c], acc);
    double key64 = xx64[p] + xx64[(size_t)b * N_ + j] - 2.0 * acc;
    float kf = (float)key64;                   // f32 grid = ref's comparison grid
    unsigned int mk = __float_as_uint(kf);
    mk ^= ((unsigned)((int)mk >> 31) | 0x80000000u);   // monotone map
    comp = ((unsigned long long)mk << 32) | (unsigned)j;  // tie -> HIGHER j wins
  }
  for (int r20 = 0; r20 < K_; ++r20) {
    unsigned long long best = comp;
#pragma unroll
    for (int off = 32; off; off >>= 1) {
      unsigned long long o2 = __shfl_xor(best, off);
      if (o2 > best) best = o2;
    }
    if (comp == best && comp != 0ull) {
      idxOut[p * K_ + r20] = (int)(comp & 0x7FFu);
      comp = 0ull;
    }
  }
}

// ---------------------------------------------------------------------------
// gather: h[k][o] = HC[p][o] + Y[idx_k][o]; max/min over k; channel sums
// ---------------------------------------------------------------------------
__global__ __launch_bounds__(256) void gather_kernel(
    const float* __restrict__ HC, const float* __restrict__ Y,
    const int* __restrict__ idx,
    float* __restrict__ HMAX, float* __restrict__ HMIN, float* __restrict__ SUMS)
{
  __shared__ float bs[64], bs2[64];
  int t = threadIdx.x;
  if (t < 64) { bs[t] = 0.f; bs2[t] = 0.f; }
  __syncthreads();
  int lane = t & 63, w = t >> 6;
  float s = 0.f, s2 = 0.f;
  for (int q = 0; q < 4; ++q) {
    size_t pp = (size_t)blockIdx.x * 16 + w * 4 + q;
    int b = (int)(pp >> 11);
    float hc = HC[pp * 64 + lane];
    float mx = -1e30f, mn = 1e30f;
    const int* ip = idx + pp * K_;
#pragma unroll
    for (int k = 0; k < K_; ++k) {
      int j = ip[k];
      float y = Y[((size_t)b * N_ + j) * 64 + lane];
      float h = hc + y;
      mx = fmaxf(mx, h);
      mn = fminf(mn, h);
      s += h;
      s2 += h * h;
    }
    HMAX[pp * 64 + lane] = mx;
    HMIN[pp * 64 + lane] = mn;
  }
  atomicAdd(&bs[lane], s);
  atomicAdd(&bs2[lane], s2);
  __syncthreads();
  if (t < 64) {
    atomicAdd(&SUMS[t], bs[t]);
    atomicAdd(&SUMS[64 + t], bs2[t]);
  }
}

// ---------------------------------------------------------------------------
// final: per-channel affine from batch stats, LeakyReLU, max/min pick,
// transpose [b][n][o] -> out[b][o][n] via LDS tile.
// ---------------------------------------------------------------------------
__global__ __launch_bounds__(256) void final_kernel(
    const float* __restrict__ HMAX, const float* __restrict__ HMIN,
    const float* __restrict__ SUMS, const float* __restrict__ gamma,
    const float* __restrict__ beta, float* __restrict__ out)
{
  __shared__ float sc[64], sh[64];
  __shared__ float T[64][65];
  int t = threadIdx.x;
  if (t < 64) {
    const float cnt = (float)((size_t)B_ * N_ * K_);   // 655360
    float mean = SUMS[t] / cnt;
    float var = SUMS[64 + t] / cnt - mean * mean;
    float scale = gamma[t] * (1.0f / sqrtf(var + 1e-5f));
    sc[t] = scale;
    sh[t] = beta[t] - mean * scale;
  }
  __syncthreads();
  int b = blockIdx.x >> 5;
  int n0 = (blockIdx.x & 31) * 64;
  int o = t & 63;
  int sub = t >> 6;                       // 0..3
  float scl = sc[o], shf = sh[o];
  for (int r = 0; r < 16; ++r) {
    int nl = r * 4 + sub;
    size_t pp = (size_t)b * N_ + n0 + nl;
    float mx = HMAX[pp * 64 + o];
    float mn = HMIN[pp * 64 + o];
    float hv = (scl >= 0.f) ? mx : mn;
    float vv = hv * scl + shf;
    vv = (vv >= 0.f) ? vv : 0.2f * vv;
    T[o][nl] = vv;
  }
  __syncthreads();
  for (int r = 0; r < 16; ++r) {
    int ol = r * 4 + sub;
    out[((size_t)b * 64 + ol) * N_ + n0 + (t & 63)] = T[ol][t & 63];
  }
}

// ---------------------------------------------------------------------------
extern "C" void kernel_launch(void* const* d_in, const int* in_sizes, int n_in,
                              void* d_out, int out_size, void* d_ws, size_t ws_size,
                              hipStream_t stream)
{
  const float* x     = (const float*)d_in[0];
  const float* W     = (const float*)d_in[1];
  const float* bias  = (const float*)d_in[2];
  const float* gamma = (const float*)d_in[3];
  const float* beta  = (const float*)d_in[4];
  float* out = (float*)d_out;
  float* ws = (float*)d_ws;

  size_t off = 0;
  float* xx    = ws + off; off += P_;                    // 32768
  float* HC    = ws + off; off += (size_t)P_ * 64;
  float* Y     = ws + off; off += (size_t)P_ * 64;
  float* HMAX  = ws + off; off += (size_t)P_ * 64;
  float* HMIN  = ws + off; off += (size_t)P_ * 64;
  float* SUMS  = ws + off; off += 128;
  int*   idx   = (int*)(ws + off); off += (size_t)P_ * K_;
  double* xx64 = (double*)(ws + off); off += (size_t)P_ * 2;   // off even -> 8B aligned
  float* dist  = ws + off;                               // chunked dist area
  size_t fixedFloats = off;
  size_t availFloats = (ws_size / 4 > fixedFloats) ? (ws_size / 4 - fixedFloats) : 0;
  int NB = (int)(availFloats / ((size_t)N_ * N_));
  if (NB < 1) NB = 1;
  if (NB > B_) NB = B_;

  hipMemsetAsync(SUMS, 0, 128 * sizeof(float), stream);
  proj_kernel<<<P_ / 64, 256, 0, stream>>>(x, W, bias, xx, xx64, HC, Y);
  for (int b0 = 0; b0 < B_; b0 += NB) {
    int nb = (B_ - b0 < NB) ? (B_ - b0) : NB;
    dist_kernel<<<dim3(16, 16, nb), 256, 0, stream>>>(x, xx, dist, b0);
    topk_kernel<<<nb * N_, 64, 0, stream>>>(dist, x, xx64, idx, b0);
  }
  gather_kernel<<<P_ / 16, 256, 0, stream>>>(HC, Y, idx, HMAX, HMIN, SUMS);
  final_kernel<<<B_ * (N_ / 64), 256, 0, stream>>>(HMAX, HMIN, SUMS, gamma, beta, out);
}

// Round 8
// 506.338 us; speedup vs baseline: 1.1526x; 1.1526x over previous
//
#include <hip/hip_runtime.h>
#include <cstdint>
#include <math.h>

#define B_ 16
#define N_ 2048
#define C_ 64
#define O_ 64
#define K_ 20
#define P_ (B_*N_)   // 32768 positions
#define MSEL 40      // minimum screening superset handed to exact re-rank

// ---------------------------------------------------------------------------
// proj: xx[p] (f32 screen + f64 exact); HC[p][o] = W[o,0:64].x_p + bias[o];
//       Y[p][o] = W[o,64:128].x_p
// ---------------------------------------------------------------------------
__global__ __launch_bounds__(256) void proj_kernel(
    const float* __restrict__ x, const float* __restrict__ W,
    const float* __restrict__ bias,
    float* __restrict__ xx, double* __restrict__ xx64,
    float* __restrict__ HC, float* __restrict__ Y)
{
  __shared__ float Wt[128][65];      // [c2][o], padded
  int t = threadIdx.x;
#pragma unroll
  for (int i = 0; i < 32; ++i) {
    int flat = t + 256 * i;          // o = flat>>7, c2 = flat&127
    Wt[flat & 127][flat >> 7] = W[flat];
  }
  __syncthreads();
  int lane = t & 63;
  int w = t >> 6;
  float bo = bias[lane];
  int pbase = blockIdx.x * 64 + w * 16;
  for (int g = 0; g < 4; ++g) {
    int p0 = pbase + g * 4;
    float xv0 = x[(size_t)(p0 + 0) * 64 + lane];
    float xv1 = x[(size_t)(p0 + 1) * 64 + lane];
    float xv2 = x[(size_t)(p0 + 2) * 64 + lane];
    float xv3 = x[(size_t)(p0 + 3) * 64 + lane];
    float hc0 = bo, hc1 = bo, hc2 = bo, hc3 = bo;
    float y0 = 0.f, y1 = 0.f, y2 = 0.f, y3 = 0.f;
#pragma unroll
    for (int c = 0; c < 64; ++c) {
      float w1 = Wt[c][lane];
      float w2 = Wt[64 + c][lane];
      float a0 = __shfl(xv0, c);
      float a1 = __shfl(xv1, c);
      float a2 = __shfl(xv2, c);
      float a3 = __shfl(xv3, c);
      hc0 += a0 * w1; y0 += a0 * w2;
      hc1 += a1 * w1; y1 += a1 * w2;
      hc2 += a2 * w1; y2 += a2 * w2;
      hc3 += a3 * w1; y3 += a3 * w2;
    }
    HC[(size_t)(p0 + 0) * 64 + lane] = hc0;
    HC[(size_t)(p0 + 1) * 64 + lane] = hc1;
    HC[(size_t)(p0 + 2) * 64 + lane] = hc2;
    HC[(size_t)(p0 + 3) * 64 + lane] = hc3;
    Y[(size_t)(p0 + 0) * 64 + lane] = y0;
    Y[(size_t)(p0 + 1) * 64 + lane] = y1;
    Y[(size_t)(p0 + 2) * 64 + lane] = y2;
    Y[(size_t)(p0 + 3) * 64 + lane] = y3;
    // row norms in f64 (exact re-rank uses these)
    double s0 = (double)xv0 * xv0, s1 = (double)xv1 * xv1;
    double s2 = (double)xv2 * xv2, s3 = (double)xv3 * xv3;
#pragma unroll
    for (int off = 32; off; off >>= 1) {
      s0 += __shfl_xor(s0, off);
      s1 += __shfl_xor(s1, off);
      s2 += __shfl_xor(s2, off);
      s3 += __shfl_xor(s3, off);
    }
    if (lane < 4) {
      double sv = (lane == 0) ? s0 : (lane == 1) ? s1 : (lane == 2) ? s2 : s3;
      xx[p0 + lane] = (float)sv;
      xx64[p0 + lane] = sv;
    }
  }
}

// ---------------------------------------------------------------------------
// dist: f32 screening, per batch, tile 128x128, 8x8 micro-tile per thread.
// ---------------------------------------------------------------------------
__global__ __launch_bounds__(256) void dist_kernel(
    const float* __restrict__ x, const float* __restrict__ xx,
    float* __restrict__ dist, int b0)
{
  int b = b0 + blockIdx.z;
  const float* xb = x + (size_t)b * N_ * 64;
  const float* xxb = xx + (size_t)b * N_;
  int it = blockIdx.y * 128, jt = blockIdx.x * 128;
  __shared__ float Xi[64][128];
  __shared__ float Xj[64][128];
  int t = threadIdx.x;
  {
    int r = t >> 1, half = t & 1;
    const float* si = xb + (size_t)(it + r) * 64 + half * 32;
    const float* sj = xb + (size_t)(jt + r) * 64 + half * 32;
#pragma unroll
    for (int q = 0; q < 8; ++q) {
      float4 vi = *(const float4*)(si + q * 4);
      float4 vj = *(const float4*)(sj + q * 4);
      int c0 = half * 32 + q * 4;
      Xi[c0 + 0][r] = vi.x; Xi[c0 + 1][r] = vi.y;
      Xi[c0 + 2][r] = vi.z; Xi[c0 + 3][r] = vi.w;
      Xj[c0 + 0][r] = vj.x; Xj[c0 + 1][r] = vj.y;
      Xj[c0 + 2][r] = vj.z; Xj[c0 + 3][r] = vj.w;
    }
  }
  __syncthreads();
  int tx = t & 15, ty = t >> 4;
  float acc[8][8];
#pragma unroll
  for (int i = 0; i < 8; ++i)
#pragma unroll
    for (int j = 0; j < 8; ++j) acc[i][j] = 0.f;
#pragma unroll 4
  for (int c = 0; c < 64; ++c) {
    float4 a0 = *(const float4*)&Xi[c][ty * 8];
    float4 a1 = *(const float4*)&Xi[c][ty * 8 + 4];
    float4 b0v = *(const float4*)&Xj[c][tx * 8];
    float4 b1v = *(const float4*)&Xj[c][tx * 8 + 4];
    float av[8] = {a0.x, a0.y, a0.z, a0.w, a1.x, a1.y, a1.z, a1.w};
    float bv[8] = {b0v.x, b0v.y, b0v.z, b0v.w, b1v.x, b1v.y, b1v.z, b1v.w};
#pragma unroll
    for (int i = 0; i < 8; ++i)
#pragma unroll
      for (int j = 0; j < 8; ++j) acc[i][j] += av[i] * bv[j];
  }
  float xi[8], xj[8];
#pragma unroll
  for (int i = 0; i < 8; ++i) xi[i] = xxb[it + ty * 8 + i];
#pragma unroll
  for (int j = 0; j < 8; ++j) xj[j] = xxb[jt + tx * 8 + j];
  float* drow = dist + ((size_t)blockIdx.z * N_ + (it + ty * 8)) * N_ + jt + tx * 8;
#pragma unroll
  for (int i = 0; i < 8; ++i) {
    float4 o0, o1;
    o0.x = (xi[i] + xj[0]) - 2.f * acc[i][0];
    o0.y = (xi[i] + xj[1]) - 2.f * acc[i][1];
    o0.z = (xi[i] + xj[2]) - 2.f * acc[i][2];
    o0.w = (xi[i] + xj[3]) - 2.f * acc[i][3];
    o1.x = (xi[i] + xj[4]) - 2.f * acc[i][4];
    o1.y = (xi[i] + xj[5]) - 2.f * acc[i][5];
    o1.z = (xi[i] + xj[6]) - 2.f * acc[i][6];
    o1.w = (xi[i] + xj[7]) - 2.f * acc[i][7];
    *(float4*)(drow + (size_t)i * N_) = o0;
    *(float4*)(drow + (size_t)i * N_ + 4) = o1;
  }
}

// ---------------------------------------------------------------------------
// topk: stage 1 = linear-value histogram select (256 bins on [min,max] of the
// remaining members; recurse into boundary bin until it fits in 64 slots).
// No exponent clustering -> near-zero LDS atomic contention. Hands nSel in
// [40,64] candidates (value-complete suffix set) to stage 2.
// stage 2 = exact f64 keys; order (f32(key) desc, index desc)  [R7 semantics]
// ---------------------------------------------------------------------------
__global__ __launch_bounds__(64) void topk_kernel(
    const float* __restrict__ dist, const float* __restrict__ x,
    const double* __restrict__ xx64, int* __restrict__ idxOut, int b0)
{
  int row = blockIdx.x;
  size_t p = (size_t)b0 * N_ + row;
  int b = (int)(p >> 11);
  const float* drow = dist + (size_t)row * N_;
  int lane = threadIdx.x;
  __shared__ int hist[256];
  __shared__ int selI[64];
  __shared__ double sxd[64];

  float v[32];
#pragma unroll
  for (int s = 0; s < 32; ++s) v[s] = drow[lane + 64 * s];

  unsigned long long ltm = (1ull << lane) - 1ull;
  unsigned memb = 0xFFFFFFFFu;       // bit s: element (lane + 64 s) still a member
  int defCount = 0, nSel = 0;
  bool done = false;

  for (int level = 0; level < 4 && !done; ++level) {
    // min/max over remaining members
    float mn = 3.4e38f, mx = -3.4e38f;
#pragma unroll
    for (int s = 0; s < 32; ++s)
      if (memb & (1u << s)) { mn = fminf(mn, v[s]); mx = fmaxf(mx, v[s]); }
#pragma unroll
    for (int off = 32; off; off >>= 1) {
      mn = fminf(mn, __shfl_xor(mn, off));
      mx = fmaxf(mx, __shfl_xor(mx, off));
    }
    if (!(mn < mx)) break;           // remaining members all tied -> fallback
    float lo = mn, scale = 255.0f / (mx - mn);
    hist[lane] = 0; hist[lane + 64] = 0; hist[lane + 128] = 0; hist[lane + 192] = 0;
    __syncthreads();
#pragma unroll
    for (int s = 0; s < 32; ++s)
      if (memb & (1u << s)) {
        int bn = (int)((v[s] - lo) * scale);
        bn = bn > 255 ? 255 : bn;
        atomicAdd(&hist[bn], 1);
      }
    __syncthreads();
    int need = MSEL - defCount;
    int h0 = hist[4 * lane], h1 = hist[4 * lane + 1];
    int h2 = hist[4 * lane + 2], h3 = hist[4 * lane + 3];
    int laneTot = h0 + h1 + h2 + h3;
    int vsum = laneTot;
#pragma unroll
    for (int off = 1; off < 64; off <<= 1) {
      int nv = __shfl_down(vsum, off);
      if (lane + off < 64) vsum += nv;
    }
    int S = vsum - laneTot;          // count in bins above this lane's quartet
    int a3 = S, a2 = S + h3, a1 = a2 + h2, a0 = a1 + h1;
    int ksel = -1;
    if (a0 < need && a0 + h0 >= need) ksel = 0;
    if (a1 < need && a1 + h1 >= need) ksel = 1;
    if (a2 < need && a2 + h2 >= need) ksel = 2;
    if (a3 < need && a3 + h3 >= need) ksel = 3;
    unsigned long long bm = __ballot(ksel >= 0);
    int lsel = __ffsll((long long)bm) - 1;
    int kk = __shfl(ksel, lsel);
    int Bstar = 4 * lsel + kk;
    // collect definite members (bin > Bstar); membership shrinks to boundary bin
    int cnt = 0;
#pragma unroll
    for (int s = 0; s < 32; ++s) {
      int bn = -1;
      if (memb & (1u << s)) {
        bn = (int)((v[s] - lo) * scale);
        bn = bn > 255 ? 255 : bn;
      }
      bool dc = bn > Bstar;
      unsigned long long mask = __ballot(dc);
      if (dc) selI[defCount + cnt + __popcll(mask & ltm)] = lane + 64 * s;
      cnt += __popcll(mask);
      if (bn != Bstar) memb &= ~(1u << s);
    }
    defCount += cnt;
    // if the boundary bin fits in the remaining slots, take all of it
    {
      int myc = __popc(memb);
      int tot = myc;
#pragma unroll
      for (int off = 32; off; off >>= 1) tot += __shfl_xor(tot, off);
      if (tot <= 64 - defCount) {
        int cc = 0;
#pragma unroll
        for (int s = 0; s < 32; ++s) {
          bool m = (memb >> s) & 1u;
          unsigned long long mask = __ballot(m);
          if (m) selI[defCount + cc + __popcll(mask & ltm)] = lane + 64 * s;
          cc += __popcll(mask);
        }
        nSel = defCount + cc;
        done = true;
      }
    }
  }
  if (!done) {
    // tied / unresolved: fill remaining slots with HIGHEST-index members
    // (matches ref's reversed-stable tie preference)
    int cap = 64 - defCount, cc = 0;
#pragma unroll
    for (int s = 31; s >= 0; --s) {
      bool m = (memb >> s) & 1u;
      unsigned long long mask = __ballot(m);
      if (m) {
        unsigned long long hm = (lane == 63) ? 0ull : (~0ull << (lane + 1));
        int pos = cc + __popcll(mask & hm);
        if (pos < cap) selI[defCount + pos] = lane + 64 * s;
      }
      cc += __popcll(mask);
    }
    nSel = defCount + (cc < cap ? cc : cap);
  }
  __syncthreads();
  // ---- stage 2: exact f64 keys; order (f32(key) desc, index DESC) ----
  sxd[lane] = (double)x[p * 64 + lane];
  __syncthreads();
  unsigned long long comp = 0ull;
  if (lane < nSel) {
    int j = selI[lane];
    const float* xj = x + ((size_t)b * N_ + j) * 64;
    double acc = 0.0;
#pragma unroll 8
    for (int c = 0; c < 64; ++c) acc = fma((double)xj[c], sxd[c], acc);
    double key64 = xx64[p] + xx64[(size_t)b * N_ + j] - 2.0 * acc;
    float kf = (float)key64;                   // f32 grid = ref's comparison grid
    unsigned int mk = __float_as_uint(kf);
    mk ^= ((unsigned)((int)mk >> 31) | 0x80000000u);   // monotone map
    comp = ((unsigned long long)mk << 32) | (unsigned)j;  // tie -> HIGHER j wins
  }
  for (int r20 = 0; r20 < K_; ++r20) {
    unsigned long long best = comp;
#pragma unroll
    for (int off = 32; off; off >>= 1) {
      unsigned long long o2 = __shfl_xor(best, off);
      if (o2 > best) best = o2;
    }
    if (comp == best && comp != 0ull) {
      idxOut[p * K_ + r20] = (int)(comp & 0x7FFu);
      comp = 0ull;
    }
  }
}

// ---------------------------------------------------------------------------
// gather: h[k][o] = HC[p][o] + Y[idx_k][o]; max/min over k; channel sums
// ---------------------------------------------------------------------------
__global__ __launch_bounds__(256) void gather_kernel(
    const float* __restrict__ HC, const float* __restrict__ Y,
    const int* __restrict__ idx,
    float* __restrict__ HMAX, float* __restrict__ HMIN, float* __restrict__ SUMS)
{
  __shared__ float bs[64], bs2[64];
  int t = threadIdx.x;
  if (t < 64) { bs[t] = 0.f; bs2[t] = 0.f; }
  __syncthreads();
  int lane = t & 63, w = t >> 6;
  float s = 0.f, s2 = 0.f;
  for (int q = 0; q < 4; ++q) {
    size_t pp = (size_t)blockIdx.x * 16 + w * 4 + q;
    int b = (int)(pp >> 11);
    float hc = HC[pp * 64 + lane];
    float mx = -1e30f, mn = 1e30f;
    const int* ip = idx + pp * K_;
#pragma unroll
    for (int k = 0; k < K_; ++k) {
      int j = ip[k];
      float y = Y[((size_t)b * N_ + j) * 64 + lane];
      float h = hc + y;
      mx = fmaxf(mx, h);
      mn = fminf(mn, h);
      s += h;
      s2 += h * h;
    }
    HMAX[pp * 64 + lane] = mx;
    HMIN[pp * 64 + lane] = mn;
  }
  atomicAdd(&bs[lane], s);
  atomicAdd(&bs2[lane], s2);
  __syncthreads();
  if (t < 64) {
    atomicAdd(&SUMS[t], bs[t]);
    atomicAdd(&SUMS[64 + t], bs2[t]);
  }
}

// ---------------------------------------------------------------------------
// final: per-channel affine from batch stats, LeakyReLU, max/min pick,
// transpose [b][n][o] -> out[b][o][n] via LDS tile.
// ---------------------------------------------------------------------------
__global__ __launch_bounds__(256) void final_kernel(
    const float* __restrict__ HMAX, const float* __restrict__ HMIN,
    const float* __restrict__ SUMS, const float* __restrict__ gamma,
    const float* __restrict__ beta, float* __restrict__ out)
{
  __shared__ float sc[64], sh[64];
  __shared__ float T[64][65];
  int t = threadIdx.x;
  if (t < 64) {
    const float cnt = (float)((size_t)B_ * N_ * K_);   // 655360
    float mean = SUMS[t] / cnt;
    float var = SUMS[64 + t] / cnt - mean * mean;
    float scale = gamma[t] * (1.0f / sqrtf(var + 1e-5f));
    sc[t] = scale;
    sh[t] = beta[t] - mean * scale;
  }
  __syncthreads();
  int b = blockIdx.x >> 5;
  int n0 = (blockIdx.x & 31) * 64;
  int o = t & 63;
  int sub = t >> 6;                       // 0..3
  float scl = sc[o], shf = sh[o];
  for (int r = 0; r < 16; ++r) {
    int nl = r * 4 + sub;
    size_t pp = (size_t)b * N_ + n0 + nl;
    float mx = HMAX[pp * 64 + o];
    float mn = HMIN[pp * 64 + o];
    float hv = (scl >= 0.f) ? mx : mn;
    float vv = hv * scl + shf;
    vv = (vv >= 0.f) ? vv : 0.2f * vv;
    T[o][nl] = vv;
  }
  __syncthreads();
  for (int r = 0; r < 16; ++r) {
    int ol = r * 4 + sub;
    out[((size_t)b * 64 + ol) * N_ + n0 + (t & 63)] = T[ol][t & 63];
  }
}

// ---------------------------------------------------------------------------
extern "C" void kernel_launch(void* const* d_in, const int* in_sizes, int n_in,
                              void* d_out, int out_size, void* d_ws, size_t ws_size,
                              hipStream_t stream)
{
  const float* x     = (const float*)d_in[0];
  const float* W     = (const float*)d_in[1];
  const float* bias  = (const float*)d_in[2];
  const float* gamma = (const float*)d_in[3];
  const float* beta  = (const float*)d_in[4];
  float* out = (float*)d_out;
  float* ws = (float*)d_ws;

  size_t off = 0;
  float* xx    = ws + off; off += P_;                    // 32768
  float* HC    = ws + off; off += (size_t)P_ * 64;
  float* Y     = ws + off; off += (size_t)P_ * 64;
  float* HMAX  = ws + off; off += (size_t)P_ * 64;
  float* HMIN  = ws + off; off += (size_t)P_ * 64;
  float* SUMS  = ws + off; off += 128;
  int*   idx   = (int*)(ws + off); off += (size_t)P_ * K_;
  double* xx64 = (double*)(ws + off); off += (size_t)P_ * 2;   // off even -> 8B aligned
  float* dist  = ws + off;                               // chunked dist area
  size_t fixedFloats = off;
  size_t availFloats = (ws_size / 4 > fixedFloats) ? (ws_size / 4 - fixedFloats) : 0;
  int NB = (int)(availFloats / ((size_t)N_ * N_));
  if (NB < 1) NB = 1;
  if (NB > 4) NB = 4;          // keep dist chunk (<=64 MB) L3-resident for topk

  hipMemsetAsync(SUMS, 0, 128 * sizeof(float), stream);
  proj_kernel<<<P_ / 64, 256, 0, stream>>>(x, W, bias, xx, xx64, HC, Y);
  for (int b0 = 0; b0 < B_; b0 += NB) {
    int nb = (B_ - b0 < NB) ? (B_ - b0) : NB;
    dist_kernel<<<dim3(16, 16, nb), 256, 0, stream>>>(x, xx, dist, b0);
    topk_kernel<<<nb * N_, 64, 0, stream>>>(dist, x, xx64, idx, b0);
  }
  gather_kernel<<<P_ / 16, 256, 0, stream>>>(HC, Y, idx, HMAX, HMIN, SUMS);
  final_kernel<<<B_ * (N_ / 64), 256, 0, stream>>>(HMAX, HMIN, SUMS, gamma, beta, out);
}